// Round 1
// baseline (743.856 us; speedup 1.0000x reference)
//
#include <hip/hip_runtime.h>
#include <hip/hip_bf16.h>

#define S_LEN 1024
#define NB 8
#define NC 768
#define NH 8
#define HD 96
#define NMLP 3072
#define SC (S_LEN*NC)        // 786432
#define BS (NB*S_LEN)        // 8192

typedef __attribute__((ext_vector_type(8))) unsigned short u16x8;
typedef __attribute__((ext_vector_type(8))) __bf16 bf16x8;
typedef __attribute__((ext_vector_type(4))) float f32x4;

__device__ __forceinline__ unsigned short f2b(float f) {
  union { __hip_bfloat16 h; unsigned short u; } cvt;
  cvt.h = __float2bfloat16(f);
  return cvt.u;
}

// ---------------------------------------------------------------------------
// Generic bf16 MFMA GEMM:  C = A(MxK) * B(KxN), B given TRANSPOSED (Bt: NxK).
// 128x128 tile, BK=32, 4 waves (2x2), each wave 64x64 = 4x4 fragments.
// EPI: 0 = store bf16
//      1 = store f32
//      2 = +bias, exact GELU, store bf16
//      3 = +residual, store f32
//      4 = +bias +residual, store f32
// ---------------------------------------------------------------------------
template<int EPI>
__global__ __launch_bounds__(256)
void gemm_bt(const unsigned short* __restrict__ A, int lda, long sAz,
             const unsigned short* __restrict__ Bt, int ldb, long sBz,
             void* __restrict__ Cv, int ldc, long sCz,
             int M, int N, int K,
             const float* __restrict__ bias,
             const float* __restrict__ residual, int ldr)
{
  __shared__ unsigned short As[128*40];   // +8 pad: 80B row stride, 2-way bank alias (free)
  __shared__ unsigned short Bs[128*40];
  const int tid = threadIdx.x;
  const int lane = tid & 63;
  const int wid = tid >> 6;
  const int wm = wid & 1, wn = wid >> 1;
  const int r15 = lane & 15, g = lane >> 4;
  const int z = blockIdx.z;
  A  += (long)z * sAz;
  Bt += (long)z * sBz;
  const int tm = blockIdx.x * 128;
  const int tn = blockIdx.y * 128;

  f32x4 acc[4][4];
  #pragma unroll
  for (int m = 0; m < 4; ++m)
    #pragma unroll
    for (int n = 0; n < 4; ++n)
      acc[m][n] = (f32x4){0.f, 0.f, 0.f, 0.f};

  for (int k0 = 0; k0 < K; k0 += 32) {
    #pragma unroll
    for (int it = 0; it < 2; ++it) {
      const int vi = it*256 + tid;
      const int row = vi >> 2;
      const int c8 = (vi & 3) << 3;
      u16x8 va = *(const u16x8*)(A + (long)(tm + row)*lda + k0 + c8);
      *(u16x8*)(As + row*40 + c8) = va;
      u16x8 vb = {0,0,0,0,0,0,0,0};
      if (tn + row < N)
        vb = *(const u16x8*)(Bt + (long)(tn + row)*ldb + k0 + c8);
      *(u16x8*)(Bs + row*40 + c8) = vb;
    }
    __syncthreads();
    bf16x8 af[4], bfr[4];
    #pragma unroll
    for (int m = 0; m < 4; ++m)
      af[m] = *(const bf16x8*)(As + (wm*64 + m*16 + r15)*40 + g*8);
    #pragma unroll
    for (int n = 0; n < 4; ++n)
      bfr[n] = *(const bf16x8*)(Bs + (wn*64 + n*16 + r15)*40 + g*8);
    #pragma unroll
    for (int m = 0; m < 4; ++m)
      #pragma unroll
      for (int n = 0; n < 4; ++n)
        acc[m][n] = __builtin_amdgcn_mfma_f32_16x16x32_bf16(af[m], bfr[n], acc[m][n], 0, 0, 0);
    __syncthreads();
  }

  unsigned short* Cu = (unsigned short*)Cv + (long)z * sCz;
  float* Cf = (float*)Cv + (long)z * sCz;
  #pragma unroll
  for (int m = 0; m < 4; ++m) {
    #pragma unroll
    for (int n = 0; n < 4; ++n) {
      const int col = tn + wn*64 + n*16 + r15;
      if (col < N) {
        #pragma unroll
        for (int r = 0; r < 4; ++r) {
          const int row = tm + wm*64 + m*16 + g*4 + r;
          float v = acc[m][n][r];
          if (EPI == 2 || EPI == 4) v += bias[col];
          if (EPI == 3 || EPI == 4) v += residual[(long)row*ldr + col];
          if (EPI == 2) v = 0.5f*v*(1.0f + erff(v*0.70710678118654752f));
          if (EPI == 0 || EPI == 2) Cu[(long)row*ldc + col] = f2b(v);
          else                      Cf[(long)row*ldc + col] = v;
        }
      }
    }
  }
}

// ---------------------------------------------------------------------------
// Weight transpose + fp32->bf16 cast: W (KxN f32) -> Wt (NxK bf16)
// ---------------------------------------------------------------------------
__global__ void transpose_cast(const float* __restrict__ W, unsigned short* __restrict__ Wt,
                               int K, int N)
{
  __shared__ float tile[32][33];
  const int tx = threadIdx.x & 31, ty = threadIdx.x >> 5;   // 32x8
  const int n0 = blockIdx.x * 32, k0 = blockIdx.y * 32;
  #pragma unroll
  for (int i = 0; i < 32; i += 8)
    tile[ty + i][tx] = W[(long)(k0 + ty + i)*N + n0 + tx];
  __syncthreads();
  #pragma unroll
  for (int i = 0; i < 32; i += 8)
    Wt[(long)(n0 + ty + i)*K + k0 + tx] = f2b(tile[tx][ty + i]);
}

// V (bf16, rows of qkv) -> Vt[d][s] per (b,h)
__global__ void transpose_v(const unsigned short* __restrict__ qkv, unsigned short* __restrict__ vt)
{
  __shared__ unsigned short tile[32][33];
  const int bh = blockIdx.z, b = bh >> 3, h = bh & 7;
  const unsigned short* v = qkv + (long)b*S_LEN*3*NC + 2*NC + h*HD;
  unsigned short* o = vt + (long)bh*HD*S_LEN;
  const int s0 = blockIdx.x * 32, d0 = blockIdx.y * 32;
  const int tx = threadIdx.x & 31, ty = threadIdx.x >> 5;
  #pragma unroll
  for (int i = 0; i < 32; i += 8)
    tile[ty + i][tx] = v[(long)(s0 + ty + i)*(3*NC) + d0 + tx];
  __syncthreads();
  #pragma unroll
  for (int i = 0; i < 32; i += 8)
    o[(long)(d0 + ty + i)*S_LEN + s0 + tx] = tile[tx][ty + i];
}

// ---------------------------------------------------------------------------
// LayerNorm over whole (S,C) plane per batch: 3-kernel pipeline
// ---------------------------------------------------------------------------
__global__ void ln_part(const float* __restrict__ X, float* __restrict__ part)
{
  const int b = blockIdx.x / 96, blk = blockIdx.x % 96;
  const float4* xb = (const float4*)(X + (long)b*SC);
  float s = 0.f, s2 = 0.f;
  #pragma unroll
  for (int i = 0; i < 8; ++i) {
    float4 v = xb[blk*2048 + i*256 + threadIdx.x];
    s  += v.x + v.y + v.z + v.w;
    s2 += v.x*v.x + v.y*v.y + v.z*v.z + v.w*v.w;
  }
  #pragma unroll
  for (int o = 32; o; o >>= 1) { s += __shfl_down(s, o); s2 += __shfl_down(s2, o); }
  __shared__ float r1[4], r2[4];
  const int w = threadIdx.x >> 6;
  if ((threadIdx.x & 63) == 0) { r1[w] = s; r2[w] = s2; }
  __syncthreads();
  if (threadIdx.x == 0) {
    part[(b*96 + blk)*2]     = r1[0] + r1[1] + r1[2] + r1[3];
    part[(b*96 + blk)*2 + 1] = r2[0] + r2[1] + r2[2] + r2[3];
  }
}

__global__ void ln_fin(const float* __restrict__ part, float* __restrict__ stats)
{
  const int b = blockIdx.x;
  float s = 0.f, s2 = 0.f;
  for (int i = threadIdx.x; i < 96; i += 64) {
    s  += part[(b*96 + i)*2];
    s2 += part[(b*96 + i)*2 + 1];
  }
  #pragma unroll
  for (int o = 32; o; o >>= 1) { s += __shfl_down(s, o); s2 += __shfl_down(s2, o); }
  if (threadIdx.x == 0) {
    const float inv = 1.0f / (float)SC;
    const float mu = s * inv;
    const float var = s2 * inv - mu*mu;
    stats[b*2] = mu;
    stats[b*2 + 1] = rsqrtf(var + 1e-5f);
  }
}

__global__ void ln_apply(const float* __restrict__ X, const float* __restrict__ W,
                         const float* __restrict__ Bv, const float* __restrict__ stats,
                         unsigned short* __restrict__ out)
{
  const long i = ((long)blockIdx.x*256 + threadIdx.x) * 8;
  const int b = (int)(i / SC);
  const long r = i % SC;
  const float mu = stats[b*2], rs = stats[b*2 + 1];
  float4 x0 = *(const float4*)(X + i),  x1 = *(const float4*)(X + i + 4);
  float4 w0 = *(const float4*)(W + r),  w1 = *(const float4*)(W + r + 4);
  float4 b0 = *(const float4*)(Bv + r), b1 = *(const float4*)(Bv + r + 4);
  u16x8 o;
  o[0] = f2b((x0.x - mu)*rs*w0.x + b0.x);
  o[1] = f2b((x0.y - mu)*rs*w0.y + b0.y);
  o[2] = f2b((x0.z - mu)*rs*w0.z + b0.z);
  o[3] = f2b((x0.w - mu)*rs*w0.w + b0.w);
  o[4] = f2b((x1.x - mu)*rs*w1.x + b1.x);
  o[5] = f2b((x1.y - mu)*rs*w1.y + b1.y);
  o[6] = f2b((x1.z - mu)*rs*w1.z + b1.z);
  o[7] = f2b((x1.w - mu)*rs*w1.w + b1.w);
  *(u16x8*)(out + i) = o;
}

// ---------------------------------------------------------------------------
// Row softmax: scores f32 (rows of 1024) -> P bf16
// ---------------------------------------------------------------------------
__global__ void softmax_rows(const float* __restrict__ Sc, unsigned short* __restrict__ P)
{
  const int tid = threadIdx.x;
  const long row = blockIdx.x;
  const float4 v = ((const float4*)(Sc + row*S_LEN))[tid];
  float m = fmaxf(fmaxf(v.x, v.y), fmaxf(v.z, v.w));
  #pragma unroll
  for (int o = 32; o; o >>= 1) m = fmaxf(m, __shfl_down(m, o));
  __shared__ float red[4];
  const int w = tid >> 6, l = tid & 63;
  if (l == 0) red[w] = m;
  __syncthreads();
  m = fmaxf(fmaxf(red[0], red[1]), fmaxf(red[2], red[3]));
  float ex = __expf(v.x - m), ey = __expf(v.y - m), ez = __expf(v.z - m), ew = __expf(v.w - m);
  float s = ex + ey + ez + ew;
  #pragma unroll
  for (int o = 32; o; o >>= 1) s += __shfl_down(s, o);
  __syncthreads();
  if (l == 0) red[w] = s;
  __syncthreads();
  s = red[0] + red[1] + red[2] + red[3];
  const float inv = 1.0f / s;
  ushort4 p;
  p.x = f2b(ex*inv); p.y = f2b(ey*inv); p.z = f2b(ez*inv); p.w = f2b(ew*inv);
  ((ushort4*)(P + row*S_LEN))[tid] = p;
}

// ---------------------------------------------------------------------------
extern "C" void kernel_launch(void* const* d_in, const int* in_sizes, int n_in,
                              void* d_out, int out_size, void* d_ws, size_t ws_size,
                              hipStream_t stream) {
  const float* x      = (const float*)d_in[0];
  const float* ln1_w  = (const float*)d_in[1];
  const float* ln1_b  = (const float*)d_in[2];
  const float* ln2_w  = (const float*)d_in[3];
  const float* ln2_b  = (const float*)d_in[4];
  const float* qkv_w  = (const float*)d_in[5];
  const float* proj_w = (const float*)d_in[6];
  const float* mlp_w1 = (const float*)d_in[7];
  const float* mlp_b1 = (const float*)d_in[8];
  const float* mlp_w2 = (const float*)d_in[9];
  const float* mlp_b2 = (const float*)d_in[10];
  float* out = (float*)d_out;

  char* ws = (char*)d_ws;
  size_t off = 0;
  auto alloc = [&](size_t b) { size_t o = off; off += (b + 255) & ~(size_t)255; return o; };
  unsigned short* wqkvT  = (unsigned short*)(ws + alloc((size_t)3*NC*NC*2));     // 2304x768
  unsigned short* wprojT = (unsigned short*)(ws + alloc((size_t)NC*NC*2));       // 768x768
  unsigned short* w1T    = (unsigned short*)(ws + alloc((size_t)NMLP*NC*2));     // 3072x768
  unsigned short* w2T    = (unsigned short*)(ws + alloc((size_t)NC*NMLP*2));     // 768x3072
  unsigned short* lnbf   = (unsigned short*)(ws + alloc((size_t)BS*NC*2));       // ln1 / attnout / ln2
  const size_t qkvOff    = alloc((size_t)BS*3*NC*2);                             // 37.75 MB
  unsigned short* qkvbf  = (unsigned short*)(ws + qkvOff);
  unsigned short* vt     = (unsigned short*)(ws + alloc((size_t)NB*NH*HD*S_LEN*2)); // 12.58 MB
  unsigned short* ybf    = (unsigned short*)(ws + qkvOff);                       // overlays qkv+vt (50.33 MB)
  const size_t scOff     = alloc((size_t)NH*S_LEN*S_LEN*4);                      // 33.55 MB
  float* scores          = (float*)(ws + scOff);
  float* hbuf            = (float*)(ws + scOff);                                 // overlays scores (25.17 MB)
  unsigned short* Pbf    = (unsigned short*)(ws + alloc((size_t)NH*S_LEN*S_LEN*2));
  float* part            = (float*)(ws + alloc((size_t)NB*96*2*4));
  float* stats           = (float*)(ws + alloc((size_t)NB*2*4));
  (void)ws_size; (void)in_sizes; (void)n_in; (void)out_size;

  const dim3 blk(256);

  // weights -> bf16, transposed
  transpose_cast<<<dim3(3*NC/32, NC/32),   blk, 0, stream>>>(qkv_w,  wqkvT,  NC, 3*NC);
  transpose_cast<<<dim3(NC/32, NC/32),     blk, 0, stream>>>(proj_w, wprojT, NC, NC);
  transpose_cast<<<dim3(NMLP/32, NC/32),   blk, 0, stream>>>(mlp_w1, w1T,    NC, NMLP);
  transpose_cast<<<dim3(NC/32, NMLP/32),   blk, 0, stream>>>(mlp_w2, w2T,    NMLP, NC);

  // LN1
  ln_part<<<dim3(NB*96), blk, 0, stream>>>(x, part);
  ln_fin<<<dim3(NB), dim3(64), 0, stream>>>(part, stats);
  ln_apply<<<dim3(BS*NC/2048), blk, 0, stream>>>(x, ln1_w, ln1_b, stats, lnbf);

  // QKV GEMM: (8192x768)@(768x2304) -> bf16
  gemm_bt<0><<<dim3(BS/128, 3*NC/128, 1), blk, 0, stream>>>(
      lnbf, NC, 0, wqkvT, NC, 0, qkvbf, 3*NC, 0, BS, 3*NC, NC, nullptr, nullptr, 0);

  // V -> Vt (all batches/heads)
  transpose_v<<<dim3(S_LEN/32, HD/32, NB*NH), blk, 0, stream>>>(qkvbf, vt);

  // attention, chunked per batch
  for (int b = 0; b < NB; ++b) {
    const unsigned short* qb = qkvbf + (size_t)b*S_LEN*3*NC;
    gemm_bt<1><<<dim3(S_LEN/128, S_LEN/128, NH), blk, 0, stream>>>(
        qb, 3*NC, HD, qb + NC, 3*NC, HD, scores, S_LEN, (long)S_LEN*S_LEN,
        S_LEN, S_LEN, HD, nullptr, nullptr, 0);
    softmax_rows<<<dim3(NH*S_LEN), blk, 0, stream>>>(scores, Pbf);
    gemm_bt<0><<<dim3(S_LEN/128, 1, NH), blk, 0, stream>>>(
        Pbf, S_LEN, (long)S_LEN*S_LEN, vt + (size_t)b*NH*HD*S_LEN, S_LEN, (long)HD*S_LEN,
        lnbf + (size_t)b*S_LEN*NC, NC, HD, S_LEN, HD, S_LEN, nullptr, nullptr, 0);
  }

  // proj + residual x -> h (f32)
  gemm_bt<3><<<dim3(BS/128, NC/128, 1), blk, 0, stream>>>(
      lnbf, NC, 0, wprojT, NC, 0, hbuf, NC, 0, BS, NC, NC, nullptr, x, NC);

  // LN2 on h
  ln_part<<<dim3(NB*96), blk, 0, stream>>>(hbuf, part);
  ln_fin<<<dim3(NB), dim3(64), 0, stream>>>(part, stats);
  ln_apply<<<dim3(BS*NC/2048), blk, 0, stream>>>(hbuf, ln2_w, ln2_b, stats, lnbf);

  // MLP1: +bias, GELU -> bf16
  gemm_bt<2><<<dim3(BS/128, NMLP/128, 1), blk, 0, stream>>>(
      lnbf, NC, 0, w1T, NC, 0, ybf, NMLP, 0, BS, NMLP, NC, mlp_b1, nullptr, 0);

  // MLP2: +bias +residual h -> out (f32)
  gemm_bt<4><<<dim3(BS/128, NC/128, 1), blk, 0, stream>>>(
      ybf, NMLP, 0, w2T, NMLP, 0, out, NC, 0, BS, NC, NMLP, mlp_b2, hbuf, NC);
}

// Round 2
// 298.895 us; speedup vs baseline: 2.4887x; 2.4887x over previous
//
#include <hip/hip_runtime.h>
#include <hip/hip_bf16.h>

#define S_LEN 1024
#define NB 8
#define NC 768
#define NH 8
#define HD 96
#define NMLP 3072
#define SC (S_LEN*NC)        // 786432
#define BS (NB*S_LEN)        // 8192

typedef __attribute__((ext_vector_type(8))) unsigned short u16x8;
typedef __attribute__((ext_vector_type(4))) unsigned short u16x4;
typedef __attribute__((ext_vector_type(8))) __bf16 bf16x8;
typedef __attribute__((ext_vector_type(4))) float f32x4;

__device__ __forceinline__ unsigned short f2b(float f) {
  union { __hip_bfloat16 h; unsigned short u; } cvt;
  cvt.h = __float2bfloat16(f);
  return cvt.u;
}

// async global->LDS, 16B per lane. LDS dest = wave-uniform base + lane*16.
__device__ __forceinline__ void gload16(const unsigned short* g, unsigned short* l) {
  __builtin_amdgcn_global_load_lds(
      (const __attribute__((address_space(1))) unsigned int*)g,
      (__attribute__((address_space(3))) unsigned int*)l, 16, 0, 0);
}

// ---------------------------------------------------------------------------
// bf16 MFMA GEMM, m97 structure: C = A(MxK) * B(KxN), B given TRANSPOSED.
// 128x128 tile, BK=32, linear LDS, global_load_lds width-16 staging.
// All of M, N divisible by 128; K divisible by 32. No masks.
// EPI: 0 = store bf16
//      2 = +bias, exact GELU, store bf16
//      3 = +residual, store f32
//      4 = +bias +residual, store f32
// ---------------------------------------------------------------------------
template<int EPI>
__global__ __launch_bounds__(256, 2)
void gemm_bt(const unsigned short* __restrict__ A, int lda,
             const unsigned short* __restrict__ Bt, int ldb,
             void* __restrict__ Cv, int ldc,
             int K,
             const float* __restrict__ bias,
             const float* __restrict__ residual, int ldr)
{
  __shared__ unsigned short As[128*32];   // linear [128 rows][32 k]
  __shared__ unsigned short Bs[128*32];
  const int tid = threadIdx.x;
  const int lane = tid & 63;
  const int wid = tid >> 6;
  const int wm = wid & 1, wn = wid >> 1;
  const int r15 = lane & 15, g = lane >> 4;
  const int tm = blockIdx.x * 128;
  const int tn = blockIdx.y * 128;

  // staging: 8KB per matrix = 8 wave-issues of 1KB; this wave does 2 each.
  // lane l of issue (wid,i): row = wid*32 + i*16 + (l>>2), col = (l&3)*8
  const unsigned short* Ab = A  + (size_t)(tm + wid*32 + (lane>>2))*lda + (lane&3)*8;
  const unsigned short* Bb = Bt + (size_t)(tn + wid*32 + (lane>>2))*ldb + (lane&3)*8;

  f32x4 acc[4][4];
  #pragma unroll
  for (int m = 0; m < 4; ++m)
    #pragma unroll
    for (int n = 0; n < 4; ++n)
      acc[m][n] = (f32x4){0.f, 0.f, 0.f, 0.f};

  for (int k0 = 0; k0 < K; k0 += 32) {
    gload16(Ab + k0,                    As + (wid*2 + 0)*512);
    gload16(Ab + (size_t)16*lda + k0,   As + (wid*2 + 1)*512);
    gload16(Bb + k0,                    Bs + (wid*2 + 0)*512);
    gload16(Bb + (size_t)16*ldb + k0,   Bs + (wid*2 + 1)*512);
    __syncthreads();
    bf16x8 af[4], bfr[4];
    #pragma unroll
    for (int m = 0; m < 4; ++m)
      af[m] = *(const bf16x8*)(As + (wm*64 + m*16 + r15)*32 + g*8);
    #pragma unroll
    for (int n = 0; n < 4; ++n)
      bfr[n] = *(const bf16x8*)(Bs + (wn*64 + n*16 + r15)*32 + g*8);
    #pragma unroll
    for (int m = 0; m < 4; ++m)
      #pragma unroll
      for (int n = 0; n < 4; ++n)
        acc[m][n] = __builtin_amdgcn_mfma_f32_16x16x32_bf16(af[m], bfr[n], acc[m][n], 0, 0, 0);
    __syncthreads();
  }

  unsigned short* Cu = (unsigned short*)Cv;
  float* Cf = (float*)Cv;
  #pragma unroll
  for (int m = 0; m < 4; ++m) {
    #pragma unroll
    for (int n = 0; n < 4; ++n) {
      const int col = tn + wn*64 + n*16 + r15;
      #pragma unroll
      for (int r = 0; r < 4; ++r) {
        const int row = tm + wm*64 + m*16 + g*4 + r;
        float v = acc[m][n][r];
        if (EPI == 2 || EPI == 4) v += bias[col];
        if (EPI == 3 || EPI == 4) v += residual[(size_t)row*ldr + col];
        if (EPI == 2) v = 0.5f*v*(1.0f + erff(v*0.70710678118654752f));
        if (EPI == 0 || EPI == 2) Cu[(size_t)row*ldc + col] = f2b(v);
        else                      Cf[(size_t)row*ldc + col] = v;
      }
    }
  }
}

// ---------------------------------------------------------------------------
// Flash attention, one (b,h) x 128-q-row tile per block, 4 waves.
// Swapped QK^T: S^T = mfma(K, Q) so each lane owns full k-columns for 2 q rows.
// P^T packed to LDS via ds_write_b64; PV as O^T = V^T * P^T (all b128 reads).
// LDS: Ks 24KB (linear) + Vs 24KB (xor-swizzled) + Ps 32KB (xor-swizzled) = 80KB.
// ---------------------------------------------------------------------------
__global__ __launch_bounds__(256, 2)
void flash_attn(const unsigned short* __restrict__ qkv,   // [B][S][2304] bf16
                const unsigned short* __restrict__ vt,    // [B*H][96][1024] bf16
                unsigned short* __restrict__ outb)        // [B][S][768] bf16
{
  __shared__ unsigned short Ks[128*96];
  __shared__ unsigned short Vs[96*128];
  __shared__ unsigned short Ps[128*128];
  const int tid = threadIdx.x, lane = tid & 63, wq = tid >> 6;
  const int r15 = lane & 15, g = lane >> 4;
  const int bh = blockIdx.y, b = bh >> 3, h = bh & 7;
  const int q0 = blockIdx.x * 128;
  const int swz = (r15 & 7) << 4;
  char* PsB = (char*)Ps;
  char* VsB = (char*)Vs;

  // Q fragments in registers: qf[n][kc] = Q[q0+wq*32+n*16+r15][kc*32+g*8 ..+8]
  bf16x8 qf[2][3];
  {
    const unsigned short* qb = qkv + ((size_t)b*S_LEN + q0 + wq*32 + r15)*2304 + h*HD + g*8;
    #pragma unroll
    for (int n = 0; n < 2; ++n)
      #pragma unroll
      for (int kc = 0; kc < 3; ++kc)
        qf[n][kc] = *(const bf16x8*)(qb + (size_t)n*16*2304 + kc*32);
  }

  // staging address precompute (6 issues per wave for K and for V^T)
  int krow[6], kcol[6], vrow[6], vcol[6];
  #pragma unroll
  for (int i = 0; i < 6; ++i) {
    const int c = (wq*6 + i)*64 + lane;
    krow[i] = c / 12;            // K tile row (192B rows, 12 chunks each)
    kcol[i] = (c % 12) * 8;
    const int L = c * 16;        // V^T linear LDS byte
    const int row = L >> 8, cb = L & 255;
    vrow[i] = row;
    vcol[i] = (cb ^ ((row & 7) << 4)) >> 1;   // pre-swizzled source column
  }
  const unsigned short* kbase = qkv + (size_t)b*S_LEN*2304 + NC + h*HD;
  const unsigned short* vbase = vt + (size_t)bh*HD*S_LEN;

  f32x4 oacc[6][2];
  #pragma unroll
  for (int m = 0; m < 6; ++m) {
    oacc[m][0] = (f32x4){0.f,0.f,0.f,0.f};
    oacc[m][1] = (f32x4){0.f,0.f,0.f,0.f};
  }
  float mrun[2] = {-INFINITY, -INFINITY};
  float lrun[2] = {0.f, 0.f};

  for (int kt = 0; kt < 8; ++kt) {
    const unsigned short* ksrc = kbase + (size_t)kt*128*2304;
    const unsigned short* vsrc = vbase + kt*128;
    #pragma unroll
    for (int i = 0; i < 6; ++i) {
      gload16(ksrc + (size_t)krow[i]*2304 + kcol[i], Ks + (wq*6 + i)*512);
      gload16(vsrc + vrow[i]*1024 + vcol[i],         Vs + (wq*6 + i)*512);
    }
    __syncthreads();

    // S^T tile: [k=128][q=32 per wave]; k = m*16+g*4+reg, q = wq*32+n*16+r15
    f32x4 sacc[8][2];
    #pragma unroll
    for (int m = 0; m < 8; ++m) {
      sacc[m][0] = (f32x4){0.f,0.f,0.f,0.f};
      sacc[m][1] = (f32x4){0.f,0.f,0.f,0.f};
    }
    #pragma unroll
    for (int kc = 0; kc < 3; ++kc)
      #pragma unroll
      for (int m = 0; m < 8; ++m) {
        bf16x8 kf = *(const bf16x8*)(Ks + (m*16 + r15)*96 + kc*32 + g*8);
        sacc[m][0] = __builtin_amdgcn_mfma_f32_16x16x32_bf16(kf, qf[0][kc], sacc[m][0], 0,0,0);
        sacc[m][1] = __builtin_amdgcn_mfma_f32_16x16x32_bf16(kf, qf[1][kc], sacc[m][1], 0,0,0);
      }

    // online softmax (per-lane over 32 k + shfl over g) + P^T -> LDS
    #pragma unroll
    for (int n = 0; n < 2; ++n) {
      float pm = -INFINITY;
      #pragma unroll
      for (int m = 0; m < 8; ++m)
        #pragma unroll
        for (int r = 0; r < 4; ++r) pm = fmaxf(pm, sacc[m][n][r]);
      pm = fmaxf(pm, __shfl_xor(pm, 16));
      pm = fmaxf(pm, __shfl_xor(pm, 32));
      const float newm = fmaxf(mrun[n], pm);
      const float scale = __expf(mrun[n] - newm);
      mrun[n] = newm;
      const int qloc = wq*32 + n*16 + r15;
      float s = 0.f;
      #pragma unroll
      for (int m = 0; m < 8; ++m) {
        float e0 = __expf(sacc[m][n][0] - newm);
        float e1 = __expf(sacc[m][n][1] - newm);
        float e2 = __expf(sacc[m][n][2] - newm);
        float e3 = __expf(sacc[m][n][3] - newm);
        s += (e0 + e1) + (e2 + e3);
        u16x4 pk = { f2b(e0), f2b(e1), f2b(e2), f2b(e3) };
        *(u16x4*)(PsB + ((qloc*256 + m*32 + g*8) ^ swz)) = pk;   // Ps[q][k], 4 consec k
      }
      s += __shfl_xor(s, 16);
      s += __shfl_xor(s, 32);
      lrun[n] = lrun[n]*scale + s;
      #pragma unroll
      for (int m = 0; m < 6; ++m) oacc[m][n] *= scale;
    }

    // O^T += V^T * P^T   (d = m*16+g*4+reg, q = wq*32+n*16+r15)
    #pragma unroll
    for (int kc = 0; kc < 4; ++kc) {
      bf16x8 pf0 = *(const bf16x8*)(PsB + (((wq*32      + r15)*256 + kc*64 + g*16) ^ swz));
      bf16x8 pf1 = *(const bf16x8*)(PsB + (((wq*32 + 16 + r15)*256 + kc*64 + g*16) ^ swz));
      #pragma unroll
      for (int m = 0; m < 6; ++m) {
        bf16x8 vf = *(const bf16x8*)(VsB + (((m*16 + r15)*256 + kc*64 + g*16) ^ swz));
        oacc[m][0] = __builtin_amdgcn_mfma_f32_16x16x32_bf16(vf, pf0, oacc[m][0], 0,0,0);
        oacc[m][1] = __builtin_amdgcn_mfma_f32_16x16x32_bf16(vf, pf1, oacc[m][1], 0,0,0);
      }
    }
    __syncthreads();
  }

  // epilogue: out[b][q][h*96+d] = O^T[d][q] / l[q]
  #pragma unroll
  for (int n = 0; n < 2; ++n) {
    const float inv = 1.0f / lrun[n];
    unsigned short* orow = outb + ((size_t)b*S_LEN + q0 + wq*32 + n*16 + r15)*NC + h*HD;
    #pragma unroll
    for (int m = 0; m < 6; ++m) {
      u16x4 pk = { f2b(oacc[m][n][0]*inv), f2b(oacc[m][n][1]*inv),
                   f2b(oacc[m][n][2]*inv), f2b(oacc[m][n][3]*inv) };
      *(u16x4*)(orow + m*16 + g*4) = pk;
    }
  }
}

// ---------------------------------------------------------------------------
// Weight transpose + fp32->bf16 cast: W (KxN f32) -> Wt (NxK bf16)
// ---------------------------------------------------------------------------
__global__ void transpose_cast(const float* __restrict__ W, unsigned short* __restrict__ Wt,
                               int K, int N)
{
  __shared__ float tile[32][33];
  const int tx = threadIdx.x & 31, ty = threadIdx.x >> 5;   // 32x8
  const int n0 = blockIdx.x * 32, k0 = blockIdx.y * 32;
  #pragma unroll
  for (int i = 0; i < 32; i += 8)
    tile[ty + i][tx] = W[(size_t)(k0 + ty + i)*N + n0 + tx];
  __syncthreads();
  #pragma unroll
  for (int i = 0; i < 32; i += 8)
    Wt[(size_t)(n0 + ty + i)*K + k0 + tx] = f2b(tile[tx][ty + i]);
}

// V (bf16, rows of qkv) -> Vt[d][s] per (b,h)
__global__ void transpose_v(const unsigned short* __restrict__ qkv, unsigned short* __restrict__ vt)
{
  __shared__ unsigned short tile[32][33];
  const int bh = blockIdx.z, b = bh >> 3, h = bh & 7;
  const unsigned short* v = qkv + (size_t)b*S_LEN*3*NC + 2*NC + h*HD;
  unsigned short* o = vt + (size_t)bh*HD*S_LEN;
  const int s0 = blockIdx.x * 32, d0 = blockIdx.y * 32;
  const int tx = threadIdx.x & 31, ty = threadIdx.x >> 5;
  #pragma unroll
  for (int i = 0; i < 32; i += 8)
    tile[ty + i][tx] = v[(size_t)(s0 + ty + i)*(3*NC) + d0 + tx];
  __syncthreads();
  #pragma unroll
  for (int i = 0; i < 32; i += 8)
    o[(size_t)(d0 + ty + i)*S_LEN + s0 + tx] = tile[tx][ty + i];
}

// ---------------------------------------------------------------------------
// LayerNorm over whole (S,C) plane per batch: 3-kernel pipeline
// ---------------------------------------------------------------------------
__global__ void ln_part(const float* __restrict__ X, float* __restrict__ part)
{
  const int b = blockIdx.x / 96, blk = blockIdx.x % 96;
  const float4* xb = (const float4*)(X + (size_t)b*SC);
  float s = 0.f, s2 = 0.f;
  #pragma unroll
  for (int i = 0; i < 8; ++i) {
    float4 v = xb[blk*2048 + i*256 + threadIdx.x];
    s  += v.x + v.y + v.z + v.w;
    s2 += v.x*v.x + v.y*v.y + v.z*v.z + v.w*v.w;
  }
  #pragma unroll
  for (int o = 32; o; o >>= 1) { s += __shfl_down(s, o); s2 += __shfl_down(s2, o); }
  __shared__ float r1[4], r2[4];
  const int w = threadIdx.x >> 6;
  if ((threadIdx.x & 63) == 0) { r1[w] = s; r2[w] = s2; }
  __syncthreads();
  if (threadIdx.x == 0) {
    part[(b*96 + blk)*2]     = r1[0] + r1[1] + r1[2] + r1[3];
    part[(b*96 + blk)*2 + 1] = r2[0] + r2[1] + r2[2] + r2[3];
  }
}

__global__ void ln_fin(const float* __restrict__ part, float* __restrict__ stats)
{
  const int b = blockIdx.x;
  float s = 0.f, s2 = 0.f;
  for (int i = threadIdx.x; i < 96; i += 64) {
    s  += part[(b*96 + i)*2];
    s2 += part[(b*96 + i)*2 + 1];
  }
  #pragma unroll
  for (int o = 32; o; o >>= 1) { s += __shfl_down(s, o); s2 += __shfl_down(s2, o); }
  if (threadIdx.x == 0) {
    const float inv = 1.0f / (float)SC;
    const float mu = s * inv;
    const float var = s2 * inv - mu*mu;
    stats[b*2] = mu;
    stats[b*2 + 1] = rsqrtf(var + 1e-5f);
  }
}

__global__ void ln_apply(const float* __restrict__ X, const float* __restrict__ W,
                         const float* __restrict__ Bv, const float* __restrict__ stats,
                         unsigned short* __restrict__ out)
{
  const size_t i = ((size_t)blockIdx.x*256 + threadIdx.x) * 8;
  const int b = (int)(i / SC);
  const size_t r = i % SC;
  const float mu = stats[b*2], rs = stats[b*2 + 1];
  float4 x0 = *(const float4*)(X + i),  x1 = *(const float4*)(X + i + 4);
  float4 w0 = *(const float4*)(W + r),  w1 = *(const float4*)(W + r + 4);
  float4 b0 = *(const float4*)(Bv + r), b1 = *(const float4*)(Bv + r + 4);
  u16x8 o;
  o[0] = f2b((x0.x - mu)*rs*w0.x + b0.x);
  o[1] = f2b((x0.y - mu)*rs*w0.y + b0.y);
  o[2] = f2b((x0.z - mu)*rs*w0.z + b0.z);
  o[3] = f2b((x0.w - mu)*rs*w0.w + b0.w);
  o[4] = f2b((x1.x - mu)*rs*w1.x + b1.x);
  o[5] = f2b((x1.y - mu)*rs*w1.y + b1.y);
  o[6] = f2b((x1.z - mu)*rs*w1.z + b1.z);
  o[7] = f2b((x1.w - mu)*rs*w1.w + b1.w);
  *(u16x8*)(out + i) = o;
}

// ---------------------------------------------------------------------------
extern "C" void kernel_launch(void* const* d_in, const int* in_sizes, int n_in,
                              void* d_out, int out_size, void* d_ws, size_t ws_size,
                              hipStream_t stream) {
  const float* x      = (const float*)d_in[0];
  const float* ln1_w  = (const float*)d_in[1];
  const float* ln1_b  = (const float*)d_in[2];
  const float* ln2_w  = (const float*)d_in[3];
  const float* ln2_b  = (const float*)d_in[4];
  const float* qkv_w  = (const float*)d_in[5];
  const float* proj_w = (const float*)d_in[6];
  const float* mlp_w1 = (const float*)d_in[7];
  const float* mlp_b1 = (const float*)d_in[8];
  const float* mlp_w2 = (const float*)d_in[9];
  const float* mlp_b2 = (const float*)d_in[10];
  float* out = (float*)d_out;

  char* ws = (char*)d_ws;
  size_t off = 0;
  auto alloc = [&](size_t b) { size_t o = off; off += (b + 255) & ~(size_t)255; return o; };
  unsigned short* wqkvT  = (unsigned short*)(ws + alloc((size_t)3*NC*NC*2));
  unsigned short* wprojT = (unsigned short*)(ws + alloc((size_t)NC*NC*2));
  unsigned short* w1T    = (unsigned short*)(ws + alloc((size_t)NMLP*NC*2));
  unsigned short* w2T    = (unsigned short*)(ws + alloc((size_t)NC*NMLP*2));
  unsigned short* lnbf   = (unsigned short*)(ws + alloc((size_t)BS*NC*2));       // ln1 / attnout / ln2
  const size_t qkvOff    = alloc((size_t)BS*3*NC*2);                             // 37.75 MB
  unsigned short* qkvbf  = (unsigned short*)(ws + qkvOff);
  unsigned short* vt     = (unsigned short*)(ws + alloc((size_t)NB*NH*HD*S_LEN*2)); // 12.58 MB
  unsigned short* ybf    = (unsigned short*)(ws + qkvOff);                       // overlays qkv+vt (50.33 MB)
  float* hbuf            = (float*)(ws + alloc((size_t)BS*NC*4));                // 25.17 MB
  float* part            = (float*)(ws + alloc((size_t)NB*96*2*4));
  float* stats           = (float*)(ws + alloc((size_t)NB*2*4));
  (void)ws_size; (void)in_sizes; (void)n_in; (void)out_size;

  const dim3 blk(256);

  // weights -> bf16, transposed
  transpose_cast<<<dim3(3*NC/32, NC/32),   blk, 0, stream>>>(qkv_w,  wqkvT,  NC, 3*NC);
  transpose_cast<<<dim3(NC/32, NC/32),     blk, 0, stream>>>(proj_w, wprojT, NC, NC);
  transpose_cast<<<dim3(NMLP/32, NC/32),   blk, 0, stream>>>(mlp_w1, w1T,    NC, NMLP);
  transpose_cast<<<dim3(NC/32, NMLP/32),   blk, 0, stream>>>(mlp_w2, w2T,    NMLP, NC);

  // LN1
  ln_part<<<dim3(NB*96), blk, 0, stream>>>(x, part);
  ln_fin<<<dim3(NB), dim3(64), 0, stream>>>(part, stats);
  ln_apply<<<dim3(BS*NC/2048), blk, 0, stream>>>(x, ln1_w, ln1_b, stats, lnbf);

  // QKV GEMM: (8192x768)@(768x2304) -> bf16
  gemm_bt<0><<<dim3(BS/128, 3*NC/128), blk, 0, stream>>>(
      lnbf, NC, wqkvT, NC, qkvbf, 3*NC, NC, nullptr, nullptr, 0);

  // V -> Vt
  transpose_v<<<dim3(S_LEN/32, HD/32, NB*NH), blk, 0, stream>>>(qkvbf, vt);

  // flash attention -> lnbf (attention output, bf16)
  flash_attn<<<dim3(S_LEN/128, NB*NH), blk, 0, stream>>>(qkvbf, vt, lnbf);

  // proj + residual x -> h (f32)
  gemm_bt<3><<<dim3(BS/128, NC/128), blk, 0, stream>>>(
      lnbf, NC, wprojT, NC, hbuf, NC, NC, nullptr, x, NC);

  // LN2 on h
  ln_part<<<dim3(NB*96), blk, 0, stream>>>(hbuf, part);
  ln_fin<<<dim3(NB), dim3(64), 0, stream>>>(part, stats);
  ln_apply<<<dim3(BS*NC/2048), blk, 0, stream>>>(hbuf, ln2_w, ln2_b, stats, lnbf);

  // MLP1: +bias, GELU -> bf16
  gemm_bt<2><<<dim3(BS/128, NMLP/128), blk, 0, stream>>>(
      lnbf, NC, w1T, NC, ybf, NMLP, NC, mlp_b1, nullptr, 0);

  // MLP2: +bias +residual h -> out (f32)
  gemm_bt<4><<<dim3(BS/128, NC/128), blk, 0, stream>>>(
      ybf, NMLP, w2T, NMLP, out, NC, NMLP, mlp_b2, hbuf, NC);
}